// Round 12
// baseline (478.253 us; speedup 1.0000x reference)
//
#include <hip/hip_runtime.h>
#include <math.h>

// Problem dims
#define Bn 64
#define Sn 512
#define Hn 1024
#define En 10
#define Mn (Bn*Sn)          // 32768 rows of the attention GEMM
#define KIN 1035            // H + E + 1  (xin length)
#define KP  2112            // padded LSTM K: 2059 -> 33*64

// d_out flat offsets (floats): fin(64), h_new(65536), c_new(65536), attn_w(32768), sim(640)
#define OUT_FIN 0
#define OUT_H   64
#define OUT_C   65600
#define OUT_AW  131136
#define OUT_SIM 163904

// d_ws offsets (floats)
#define WS_ENCB  0                     // 32M bf16; dead after k3b -> LSTM aliases
#define WS_WENCB 16777216              // 1M bf16
#define WS_WTS   17301504              // 64*512 fp32
#define WS_PART  17334272              // 4*32768 fp32 (k2 partials, dead after k3a)
#define WS_CTXP  17334272              // 8*64*1024 fp32 = 524288 (alias over PART; k3b after k3a)
#define WS_WDECB 17858560              // 1M bf16 = 524288 floats (dead after k1_gemm)
#define WS_H0B   18382848              // 64K bf16 = 32768 floats
#define WS_DPART 18415616              // 8*64*1024 fp32 = 524288
// end 18939904 floats = 75.8 MB
// --- aliases inside the (dead after k3b) encB region ---
// (WcatB removed: k5 now casts Wih/Whh inline during B-staging)
#define WS_GPART 4325376               // 8*64*4096 fp32
#define WS_XINB  6422528               // 64*2112 bf16

typedef __attribute__((ext_vector_type(8))) short bf16x8;
typedef __attribute__((ext_vector_type(4))) float f32x4;

#define ASYNC_CP16(gptr, lptr) \
  __builtin_amdgcn_global_load_lds((const __attribute__((address_space(1))) void*)(gptr), \
                                   (__attribute__((address_space(3))) void*)(lptr), 16, 0, 0)

static __device__ __forceinline__ unsigned short f2bf(float f) {
    union { float f; unsigned int u; } v; v.f = f;
    unsigned int r = (v.u + 0x7fffu + ((v.u >> 16) & 1u)) >> 16;
    return (unsigned short)r;
}
static __device__ __forceinline__ float bf2f(unsigned short h) {
    union { unsigned int u; float f; } v; v.u = ((unsigned int)h) << 16;
    return v.f;
}
// fast tanh: (e^{2x}-1)/(e^{2x}+1) via hw exp + hw rcp; clamp keeps e finite
static __device__ __forceinline__ float fast_tanh(float x) {
    float cx = fminf(15.f, fmaxf(-15.f, x));
    float e = __expf(2.f * cx);
    return (e - 1.f) * __builtin_amdgcn_rcpf(e + 1.f);
}

// ---------------------------------------------------------------------------
// k_cast: fp32->bf16 for enc, Wenc, Wdec, h0. 2048 elems/block.
__global__ __launch_bounds__(256) void k_cast(const float* __restrict__ enc,
                                              const float* __restrict__ Wenc,
                                              const float* __restrict__ Wdec,
                                              const float* __restrict__ h0,
                                              unsigned short* __restrict__ encB,
                                              unsigned short* __restrict__ wencB,
                                              unsigned short* __restrict__ wdecB,
                                              unsigned short* __restrict__ h0B) {
    int bid = blockIdx.x;
    const float* src; unsigned short* dst; size_t off;
    if (bid < 16384)      { src = enc;  dst = encB;  off = (size_t)bid * 2048; }
    else if (bid < 16896) { src = Wenc; dst = wencB; off = (size_t)(bid - 16384) * 2048; }
    else if (bid < 17408) { src = Wdec; dst = wdecB; off = (size_t)(bid - 16896) * 2048; }
    else                  { src = h0;   dst = h0B;   off = (size_t)(bid - 17408) * 2048; }
    off += (size_t)threadIdx.x * 8;
    float4 v0 = *(const float4*)(src + off);
    float4 v1 = *(const float4*)(src + off + 4);
    ushort4 a; a.x = f2bf(v0.x); a.y = f2bf(v0.y); a.z = f2bf(v0.z); a.w = f2bf(v0.w);
    ushort4 b; b.x = f2bf(v1.x); b.y = f2bf(v1.y); b.z = f2bf(v1.z); b.w = f2bf(v1.w);
    *(ushort4*)(dst + off)     = a;
    *(ushort4*)(dst + off + 4) = b;
}

// ---------------------------------------------------------------------------
// k1_gemm: dpart[sp][b][g] = partial of h0B[b,:] . wdecB[g,:]  (M=64,N=1024,K=1024)
// grid (8 N-tiles, 8 K-splits); block 64x128, waves 2x2 (tile 32x64), BK=64, 2 iters.
__global__ __launch_bounds__(256) void k1_gemm(const unsigned short* __restrict__ h0B,
                                               const unsigned short* __restrict__ wdecB,
                                               float* __restrict__ dpart) {
    __shared__ short As[4096];       // 8 quads * 64 rows * 8
    __shared__ short Bs[8192];       // 8 quads * 128 rows * 8

    const int n0 = blockIdx.x * 128;
    const int sp = blockIdx.y;                    // 8 K-splits x 2 BK-iters
    const int kbeg = sp * 128;
    const int tid  = threadIdx.x;
    const int wave = tid >> 6;
    const int lane = tid & 63;
    const int wr = wave >> 1;
    const int wc = wave & 1;
    const int q4 = lane >> 4;
    const int ml = lane & 15;

    f32x4 acc[2][4];
#pragma unroll
    for (int i = 0; i < 2; ++i)
#pragma unroll
        for (int j = 0; j < 4; ++j) acc[i][j] = (f32x4){0.f, 0.f, 0.f, 0.f};

    const unsigned short* bTile = wdecB + (size_t)n0 * 1024;

    for (int kk = 0; kk < 2; ++kk) {
        int k0 = kbeg + kk * 64;
        __syncthreads();
#pragma unroll
        for (int t = 0; t < 2; ++t) {
            int q = wave * 2 + t;
            ASYNC_CP16(h0B + (size_t)lane * 1024 + k0 + q * 8, &As[(q * 64) * 8]);
        }
#pragma unroll
        for (int t = 0; t < 4; ++t) {
            int cb = t * 4 + wave;
            int q  = cb >> 1;
            int mb = (cb & 1) << 6;
            ASYNC_CP16(bTile + (size_t)(mb + lane) * 1024 + k0 + q * 8,
                       &Bs[(q * 128 + mb) * 8]);
        }
        __syncthreads();
#pragma unroll
        for (int s = 0; s < 2; ++s) {
            bf16x8 af[2], bfr[4];
#pragma unroll
            for (int i = 0; i < 2; ++i)
                af[i] = *(const bf16x8*)&As[((((s << 2) + q4) * 64) + wr * 32 + (i << 4) + ml) * 8];
#pragma unroll
            for (int j = 0; j < 4; ++j)
                bfr[j] = *(const bf16x8*)&Bs[((((s << 2) + q4) * 128) + wc * 64 + (j << 4) + ml) * 8];
#pragma unroll
            for (int i = 0; i < 2; ++i)
#pragma unroll
                for (int j = 0; j < 4; ++j)
                    acc[i][j] = __builtin_amdgcn_mfma_f32_16x16x32_bf16(af[i], bfr[j], acc[i][j], 0, 0, 0);
        }
    }
#pragma unroll
    for (int i = 0; i < 2; ++i)
#pragma unroll
        for (int j = 0; j < 4; ++j)
#pragma unroll
            for (int r = 0; r < 4; ++r) {
                int m = wr * 32 + (i << 4) + q4 * 4 + r;
                int n = n0 + wc * 64 + (j << 4) + ml;
                dpart[((size_t)sp * 64 + m) * 1024 + n] = acc[i][j][r];
            }
}

// ---------------------------------------------------------------------------
// k2: bf16 MFMA attn-score GEMM + fused fast-tanh.w_val epilogue.
// REWRITE (R10): 256x256 tile, stage-ahead double-buffer (T3 minimum recipe).
// R6/R9 showed the old 2-barrier-per-K-step structure is stuck at 18% MfmaUtil
// regardless of LDS/occupancy (452 TF): staging and compute never overlap, so
// all blocks burst-load then stall together on L2 latency. Here:
//   - 512 blocks = 128 m-tiles x 4 n-tiles (XCD-chunked: 16 m-tiles/XCD, the
//     4 n-blocks of an m-tile dispatch-adjacent within one XCD).
//   - 8 waves (2M x 4N), wave tile 128x64, acc[8][4] f32x4, BK=64, 16 K-tiles.
//   - LDS 128 KB: 2 bufs x (A 32 KB + B 32 KB), quad-major layout (bank-
//     conflict-free, measured 0 conflicts in R6/R9).
//   - Loop: STAGE(t+1 -> buf[t+1 & 1]) issued BEFORE computing tile t from
//     buf[t&1]; one __syncthreads() (compiler inserts the vmcnt drain) per
//     K-tile. The staged buffer was freed at the previous barrier -> no race.
//     8 in-flight loads are covered by 24 ds_reads + 64 MFMAs of compute.
// No __launch_bounds__ min-waves (R8: it forced a 64-reg cap and spilled acc).
// LDS caps residency at 1 block/CU; per-block pipelining does the hiding.
// Spill tripwire for next profile: WRITE_SIZE must stay ~1 MB.
__global__ __launch_bounds__(512) void k2_scores(const unsigned short* __restrict__ encB,
                                                 const unsigned short* __restrict__ wencB,
                                                 const float* __restrict__ dpart,
                                                 const float* __restrict__ wval,
                                                 float* __restrict__ part) {
    __shared__ short As[2][16384];   // [buf][(q*256 + row)*8], q = k-octet 0..7
    __shared__ short Bs[2][16384];

    const int bid = blockIdx.x;               // 512
    const int xcd = bid & 7;                  // dispatch round-robin -> XCD id
    const int j   = bid >> 3;                 // 0..63: within-XCD issue order
    const int m0  = (xcd * 16 + (j >> 2)) * 256;  // contiguous m-chunk per XCD
    const int nb  = j & 3;                    // 4 N-tiles of one m-tile adjacent
    const int n0  = nb * 256;
    const int b   = m0 >> 9;                  // 256 | 512 -> b uniform per block
    const int tid  = threadIdx.x;
    const int wave = tid >> 6;                // 0..7
    const int lane = tid & 63;
    const int wr2 = wave >> 2;                // 0..1: rows wr2*128..+127
    const int wc2 = wave & 3;                 // 0..3: cols wc2*64..+63
    const int q4 = lane >> 4;
    const int ml = lane & 15;

    f32x4 acc[8][4];
#pragma unroll
    for (int i = 0; i < 8; ++i)
#pragma unroll
        for (int jj = 0; jj < 4; ++jj) acc[i][jj] = (f32x4){0.f, 0.f, 0.f, 0.f};

    const unsigned short* aTile = encB  + (size_t)m0 * 1024;
    const unsigned short* bTile = wencB + (size_t)n0 * 1024;

    // stage K-tile kt (k = kt*64..+63) into buffer bf: 64 wave-loads total
    // (8 per wave: 4 A + 4 B). Dest is wave-uniform base + lane*16B.
    auto STAGE = [&](int kt, int bf) {
        int k0 = kt * 64;
#pragma unroll
        for (int t2 = 0; t2 < 4; ++t2) {
            int c  = t2 * 8 + wave;           // 0..31
            int q  = c >> 2;                  // k-octet 0..7
            int sg = (c & 3) * 64;            // 64-row segment base
            ASYNC_CP16(aTile + (size_t)(sg + lane) * 1024 + k0 + q * 8,
                       &As[bf][(q * 256 + sg) * 8]);
            ASYNC_CP16(bTile + (size_t)(sg + lane) * 1024 + k0 + q * 8,
                       &Bs[bf][(q * 256 + sg) * 8]);
        }
    };

    STAGE(0, 0);
    __syncthreads();                          // vmcnt(0) drain + barrier

    for (int t = 0; t < 16; ++t) {
        const int cur = t & 1;
        if (t < 15) STAGE(t + 1, cur ^ 1);    // overlap: lands under compute
        bf16x8 bfr[2][4];
#pragma unroll
        for (int s = 0; s < 2; ++s)
#pragma unroll
            for (int jj = 0; jj < 4; ++jj)
                bfr[s][jj] = *(const bf16x8*)
                    &Bs[cur][(((s * 4 + q4) * 256) + wc2 * 64 + jj * 16 + ml) * 8];
#pragma unroll
        for (int i = 0; i < 8; ++i) {
            bf16x8 a0 = *(const bf16x8*)
                &As[cur][((q4 * 256) + wr2 * 128 + i * 16 + ml) * 8];
            bf16x8 a1 = *(const bf16x8*)
                &As[cur][(((4 + q4) * 256) + wr2 * 128 + i * 16 + ml) * 8];
#pragma unroll
            for (int jj = 0; jj < 4; ++jj)
                acc[i][jj] = __builtin_amdgcn_mfma_f32_16x16x32_bf16(a0, bfr[0][jj], acc[i][jj], 0, 0, 0);
#pragma unroll
            for (int jj = 0; jj < 4; ++jj)
                acc[i][jj] = __builtin_amdgcn_mfma_f32_16x16x32_bf16(a1, bfr[1][jj], acc[i][jj], 0, 0, 0);
        }
        __syncthreads();                      // per-K-tile drain + barrier
    }

    // epilogue: dec_proj = sum of 8 k1 splits; tanh()*wval row-reduced
    float dpv[4], wvv[4];
#pragma unroll
    for (int jj = 0; jj < 4; ++jj) {
        int n = n0 + wc2 * 64 + jj * 16 + ml;
        float d = 0.f;
#pragma unroll
        for (int sp = 0; sp < 8; ++sp) d += dpart[((size_t)sp * 64 + b) * 1024 + n];
        dpv[jj] = d;
        wvv[jj] = wval[n];
    }
    float* rsum = (float*)As;                 // [4 n-slices][256 rows] = 4 KB
#pragma unroll
    for (int i = 0; i < 8; ++i) {
#pragma unroll
        for (int r = 0; r < 4; ++r) {
            float p = 0.f;
#pragma unroll
            for (int jj = 0; jj < 4; ++jj) p += fast_tanh(acc[i][jj][r] + dpv[jj]) * wvv[jj];
            p += __shfl_xor(p, 1);
            p += __shfl_xor(p, 2);
            p += __shfl_xor(p, 4);
            p += __shfl_xor(p, 8);
            if (ml == 0) rsum[wc2 * 256 + wr2 * 128 + i * 16 + q4 * 4 + r] = p;
        }
    }
    __syncthreads();
    if (tid < 256)
        part[(size_t)nb * Mn + m0 + tid] =
            rsum[tid] + rsum[256 + tid] + rsum[512 + tid] + rsum[768 + tid];
}

// ---------------------------------------------------------------------------
__device__ __forceinline__ float block_sum256(float v, float* red, int tid) {
#pragma unroll
    for (int off = 1; off < 64; off <<= 1) v += __shfl_xor(v, off);
    if ((tid & 63) == 0) red[tid >> 6] = v;
    __syncthreads();
    v = red[0] + red[1] + red[2] + red[3];
    __syncthreads();
    return v;
}

// k3a: sum 4 partial slices (k2 now has 4 N-tiles of 256) -> softmax -> attn_w
__global__ __launch_bounds__(256) void k3a_softmax(const float* __restrict__ part,
                                                   float* __restrict__ wts,
                                                   float* __restrict__ out) {
    int b = blockIdx.x;
    int tid = threadIdx.x;
    __shared__ float red[8];
    int s0 = tid, s1 = tid + 256;
    float v0 = 0.f, v1 = 0.f;
#pragma unroll
    for (int nb = 0; nb < 4; ++nb) {
        v0 += part[(size_t)nb * Mn + b * 512 + s0];
        v1 += part[(size_t)nb * Mn + b * 512 + s1];
    }
    float mx = fmaxf(v0, v1);
#pragma unroll
    for (int off = 1; off < 64; off <<= 1) mx = fmaxf(mx, __shfl_xor(mx, off));
    if ((tid & 63) == 0) red[tid >> 6] = mx;
    __syncthreads();
    mx = fmaxf(fmaxf(red[0], red[1]), fmaxf(red[2], red[3]));
    __syncthreads();
    float e0 = __expf(v0 - mx), e1 = __expf(v1 - mx);
    float sm = block_sum256(e0 + e1, red, tid);
    float inv = 1.0f / sm;
    float w0 = e0 * inv, w1 = e1 * inv;
    wts[b * 512 + s0] = w0;
    wts[b * 512 + s1] = w1;
    out[OUT_AW + b * 512 + s0] = w0;
    out[OUT_AW + b * 512 + s1] = w1;
}

// k3b: ctxp[sc][b][h] = sum_{s in 64-chunk sc} w[b,s] * encB[b,s,h]  (8 S-chunks)
// Widened loads (G13): 8 B/lane (uint2 = 4 bf16); s-dim split 2-way across
// thread halves, combined via 2 KB LDS. Output layout ctxp[8][64][1024].
__global__ __launch_bounds__(256) void k3b_context(const unsigned short* __restrict__ encB,
                                                   const float* __restrict__ wts,
                                                   float* __restrict__ ctxp) {
    int b  = blockIdx.y;
    int sc = blockIdx.x >> 1;                        // 0..7
    int hh = blockIdx.x & 1;                         // h half
    int tid = threadIdx.x;
    int sr = tid >> 7;                               // 0..1: s parity
    int cl = tid & 127;                              // 0..127
    int hc = hh * 512 + cl * 4;                      // 4-col group
    const unsigned short* e = encB + (size_t)b * Sn * Hn + (size_t)sc * 64 * Hn + hc;
    const float* w = wts + b * 512 + sc * 64;
    float a0 = 0.f, a1 = 0.f, a2 = 0.f, a3 = 0.f;
#pragma unroll 8
    for (int s = sr; s < 64; s += 2) {
        uint2 p = *(const uint2*)(e + (size_t)s * 1024);
        float ws = w[s];
        a0 += ws * bf2f((unsigned short)(p.x & 0xffffu));
        a1 += ws * bf2f((unsigned short)(p.x >> 16));
        a2 += ws * bf2f((unsigned short)(p.y & 0xffffu));
        a3 += ws * bf2f((unsigned short)(p.y >> 16));
    }
    __shared__ float lds[512];                       // 2 KB
    if (sr == 1) *(float4*)&lds[cl * 4] = (float4){a0, a1, a2, a3};
    __syncthreads();
    if (sr == 0) {
        float4 o = *(const float4*)&lds[cl * 4];
        o.x += a0; o.y += a1; o.z += a2; o.w += a3;
        *(float4*)(ctxp + ((size_t)sc * 64 + b) * 1024 + hc) = o;
    }
}

// k4: ctx assembled in LDS from 8 ctxp chunks; sim[b,e'] = W_gate . (ctx . events^T).
// FUSED k_xinB: emits the bf16 LSTM input row xinB[b] directly.
__global__ __launch_bounds__(256) void k4_sim(const float* __restrict__ ctxp,
                                              const float* __restrict__ events,
                                              const float* __restrict__ Wg,
                                              const float* __restrict__ x,
                                              const float* __restrict__ h0,
                                              float* __restrict__ out,
                                              unsigned short* __restrict__ xinB) {
    int b = blockIdx.x;
    int tid = threadIdx.x, wv = tid >> 6, lane = tid & 63;
    __shared__ float cl[1024];
    __shared__ float tmp[16];
    unsigned short* xrow = xinB + (size_t)b * KP;
#pragma unroll
    for (int i = 0; i < 4; ++i) {
        int h = tid + i * 256;
        float v = 0.f;
#pragma unroll
        for (int sc = 0; sc < 8; ++sc) v += ctxp[((size_t)sc * 64 + b) * 1024 + h];
        cl[h] = v;
        xrow[h] = f2bf(v);                       // xin[0:1024] = ctx
        xrow[1035 + h] = f2bf(h0[b * 1024 + h]); // xin[1035:2059] = h0
    }
    // xin tail: x at 1034, zero pad 2059..2111
    if (tid == 0) xrow[1034] = f2bf(x[b]);
    if (tid < 53) xrow[2059 + tid] = 0;
    __syncthreads();
    for (int e = wv; e < 10; e += 4) {
        const float* ev = events + e * 1024;
        float a = 0.f;
#pragma unroll
        for (int kk = 0; kk < 1024; kk += 64) a += cl[kk + lane] * ev[kk + lane];
#pragma unroll
        for (int off = 1; off < 64; off <<= 1) a += __shfl_xor(a, off);
        if (lane == 0) tmp[e] = a;
    }
    __syncthreads();
    if (tid < 10) {
        float s2 = 0.f;
#pragma unroll
        for (int e = 0; e < 10; ++e) s2 += Wg[tid * 10 + e] * tmp[e];
        out[OUT_SIM + b * 10 + tid] = s2;
        xrow[1024 + tid] = f2bf(s2);             // xin[1024:1034] = sim
    }
}

// ---------------------------------------------------------------------------
// k5_gemm: G[64,4096] = xinB[64,KP] . Wcat[4096,KP]^T  with split-K 8.
// FUSED k_castW: Wcat gathered + f2bf-cast inline during B-staging.
__global__ __launch_bounds__(256) void k5_gemm(const unsigned short* __restrict__ xinB,
                                               const float* __restrict__ Wih,
                                               const float* __restrict__ Whh,
                                               float* __restrict__ gpart) {
    __shared__ short As[4096];
    __shared__ short Bs[8192];

    const int n0 = blockIdx.x * 128;
    const int sp = blockIdx.y;
    const int kbeg   = (sp == 0) ? 0 : (5 + (sp - 1) * 4) * 64;
    const int ksteps = (sp == 0) ? 5 : 4;
    const int tid  = threadIdx.x;
    const int wave = tid >> 6;
    const int lane = tid & 63;
    const int wr = wave >> 1;
    const int wc = wave & 1;
    const int q4 = lane >> 4;
    const int ml = lane & 15;

    f32x4 acc[2][4];
#pragma unroll
    for (int i = 0; i < 2; ++i)
#pragma unroll
        for (int j = 0; j < 4; ++j) acc[i][j] = (f32x4){0.f, 0.f, 0.f, 0.f};

    for (int kk = 0; kk < ksteps; ++kk) {
        int k0 = kbeg + kk * 64;
        __syncthreads();
#pragma unroll
        for (int t = 0; t < 2; ++t) {
            int q = wave * 2 + t;
            ASYNC_CP16(xinB + (size_t)lane * KP + k0 + q * 8, &As[(q * 64) * 8]);
        }
        // B staging: inline cast from Wih/Whh (replaces WcatB ASYNC_CP16)
#pragma unroll
        for (int t = 0; t < 4; ++t) {
            int cb = t * 4 + wave;
            int q  = cb >> 1;
            int mb = (cb & 1) << 6;
            int g  = n0 + mb + lane;          // gate row (per-lane)
            int kq = k0 + q * 8;              // wave-uniform col base
            const float* rih = Wih + (size_t)g * 1035;
            const float* rhh = Whh + (size_t)g * 1024 - 1035;   // index by k directly
            union { unsigned short us[8]; bf16x8 v; } pk;
#pragma unroll
            for (int e2 = 0; e2 < 8; ++e2) {
                int k = kq + e2;              // wave-uniform -> scalar branch
                float vv;
                if (k < 1035)      vv = rih[k];
                else if (k < 2059) vv = rhh[k];
                else               vv = 0.f;
                pk.us[e2] = f2bf(vv);
            }
            *(bf16x8*)&Bs[(q * 128 + mb + lane) * 8] = pk.v;
        }
        __syncthreads();
#pragma unroll
        for (int s = 0; s < 2; ++s) {
            bf16x8 af[2], bfr[4];
#pragma unroll
            for (int i = 0; i < 2; ++i)
                af[i] = *(const bf16x8*)&As[((((s << 2) + q4) * 64) + wr * 32 + (i << 4) + ml) * 8];
#pragma unroll
            for (int j = 0; j < 4; ++j)
                bfr[j] = *(const bf16x8*)&Bs[((((s << 2) + q4) * 128) + wc * 64 + (j << 4) + ml) * 8];
#pragma unroll
            for (int i = 0; i < 2; ++i)
#pragma unroll
                for (int j = 0; j < 4; ++j)
                    acc[i][j] = __builtin_amdgcn_mfma_f32_16x16x32_bf16(af[i], bfr[j], acc[i][j], 0, 0, 0);
        }
    }
#pragma unroll
    for (int i = 0; i < 2; ++i)
#pragma unroll
        for (int j = 0; j < 4; ++j)
#pragma unroll
            for (int r = 0; r < 4; ++r) {
                int m = wr * 32 + (i << 4) + q4 * 4 + r;
                int n = n0 + wc * 64 + (j << 4) + ml;
                gpart[((size_t)sp * 64 + m) * 4096 + n] = acc[i][j][r];
            }
}

// k56: gates = sum_sp gpart + biases -> LSTM cell -> h,c; then fused LayerNorm+fin.
__global__ __launch_bounds__(256) void k56_lstm_ln(const float* __restrict__ gpart,
                                                   const float* __restrict__ bih,
                                                   const float* __restrict__ bhh,
                                                   const float* __restrict__ c0,
                                                   const float* __restrict__ lng,
                                                   const float* __restrict__ lnb,
                                                   const float* __restrict__ Wfin,
                                                   const float* __restrict__ bfin,
                                                   float* __restrict__ out) {
    int b = blockIdx.x, tid = threadIdx.x;
    __shared__ float red[8];
    float hn[4];
#pragma unroll
    for (int r = 0; r < 4; ++r) {
        int u = tid + (r << 8);
        float g[4];
#pragma unroll
        for (int gt = 0; gt < 4; ++gt) {
            int rr = gt * 1024 + u;
            float a = bih[rr] + bhh[rr];
#pragma unroll
            for (int sp = 0; sp < 8; ++sp)
                a += gpart[((size_t)sp * 64 + b) * 4096 + rr];
            g[gt] = a;
        }
        float cp = c0[b * 1024 + u];
        float si = 1.f / (1.f + __expf(-g[0]));
        float sf = 1.f / (1.f + __expf(-g[1]));
        float so = 1.f / (1.f + __expf(-g[3]));
        float cn = sf * cp + si * tanhf(g[2]);
        hn[r] = so * tanhf(cn);
        out[OUT_H + b * 1024 + u] = hn[r];
        out[OUT_C + b * 1024 + u] = cn;
    }
    // LayerNorm + final dot
    float mu = block_sum256(hn[0] + hn[1] + hn[2] + hn[3], red, tid) * (1.f / 1024.f);
    float d0 = hn[0] - mu, d1 = hn[1] - mu, d2 = hn[2] - mu, d3 = hn[3] - mu;
    float var = block_sum256(d0 * d0 + d1 * d1 + d2 * d2 + d3 * d3, red, tid) * (1.f / 1024.f);
    float rstd = rsqrtf(var + 1e-5f);
    float acc = (d0 * rstd * lng[tid]       + lnb[tid])       * Wfin[tid]
              + (d1 * rstd * lng[tid + 256] + lnb[tid + 256]) * Wfin[tid + 256]
              + (d2 * rstd * lng[tid + 512] + lnb[tid + 512]) * Wfin[tid + 512]
              + (d3 * rstd * lng[tid + 768] + lnb[tid + 768]) * Wfin[tid + 768];
    acc = block_sum256(acc, red, tid);
    if (tid == 0) out[OUT_FIN + b] = acc + bfin[0];
}

// ---------------------------------------------------------------------------
extern "C" void kernel_launch(void* const* d_in, const int* in_sizes, int n_in,
                              void* d_out, int out_size, void* d_ws, size_t ws_size,
                              hipStream_t stream) {
    (void)in_sizes; (void)n_in; (void)out_size; (void)ws_size;
    const float* x    = (const float*)d_in[0];
    const float* h0   = (const float*)d_in[1];
    const float* c0   = (const float*)d_in[2];
    const float* enc  = (const float*)d_in[3];
    const float* Wenc = (const float*)d_in[4];
    const float* Wdec = (const float*)d_in[5];
    const float* wval = (const float*)d_in[6];
    const float* Wg   = (const float*)d_in[7];
    const float* ev   = (const float*)d_in[8];
    const float* Wih  = (const float*)d_in[9];
    const float* Whh  = (const float*)d_in[10];
    const float* bih  = (const float*)d_in[11];
    const float* bhh  = (const float*)d_in[12];
    const float* lng  = (const float*)d_in[13];
    const float* lnb  = (const float*)d_in[14];
    const float* Wfin = (const float*)d_in[15];
    const float* bfin = (const float*)d_in[16];

    float* out  = (float*)d_out;
    float* ws   = (float*)d_ws;
    unsigned short* encB  = (unsigned short*)(ws + WS_ENCB);
    unsigned short* wencB = (unsigned short*)(ws + WS_WENCB);
    unsigned short* wdecB = (unsigned short*)(ws + WS_WDECB);
    unsigned short* h0B   = (unsigned short*)(ws + WS_H0B);
    float* dpart = ws + WS_DPART;
    float* wts   = ws + WS_WTS;
    float* part  = ws + WS_PART;
    float* ctxp  = ws + WS_CTXP;                                // alias over part (dead after k3a)
    float* gpart = ws + WS_GPART;                               // alias encB (dead after k3b)
    unsigned short* xinB  = (unsigned short*)(ws + WS_XINB);    // alias encB

    k_cast     <<<17440, 256, 0, stream>>>(enc, Wenc, Wdec, h0, encB, wencB, wdecB, h0B);
    k1_gemm    <<<dim3(8, 8), 256, 0, stream>>>(h0B, wdecB, dpart);
    k2_scores  <<<512, 512, 0, stream>>>(encB, wencB, dpart, wval, part);
    k3a_softmax<<<64, 256, 0, stream>>>(part, wts, out);
    k3b_context<<<dim3(16, 64), 256, 0, stream>>>(encB, wts, ctxp);
    // encB region dead past k3b -> safe for LSTM buffers (k4 writes xinB there)
    k4_sim     <<<64, 256, 0, stream>>>(ctxp, ev, Wg, x, h0, out, xinB);
    k5_gemm    <<<dim3(32, 8), 256, 0, stream>>>(xinB, Wih, Whh, gpart);
    k56_lstm_ln<<<64, 256, 0, stream>>>(gpart, bih, bhh, c0, lng, lnb, Wfin, bfin, out);
}

// Round 13
// 469.371 us; speedup vs baseline: 1.0189x; 1.0189x over previous
//
#include <hip/hip_runtime.h>
#include <math.h>

// Problem dims
#define Bn 64
#define Sn 512
#define Hn 1024
#define En 10
#define Mn (Bn*Sn)          // 32768 rows of the attention GEMM
#define KIN 1035            // H + E + 1  (xin length)
#define KP  2112            // padded LSTM K: 2059 -> 33*64

// d_out flat offsets (floats): fin(64), h_new(65536), c_new(65536), attn_w(32768), sim(640)
#define OUT_FIN 0
#define OUT_H   64
#define OUT_C   65600
#define OUT_AW  131136
#define OUT_SIM 163904

// d_ws offsets (floats)
#define WS_ENCB  0                     // 32M bf16; dead after k3b -> LSTM aliases
#define WS_WENCB 16777216              // 1M bf16
#define WS_WTS   17301504              // 64*512 fp32
#define WS_PART  17334272              // 4*32768 fp32 (k2 partials, dead after k3a)
#define WS_CTXP  17334272              // 8*64*1024 fp32 = 524288 (alias over PART; k3b after k3a)
#define WS_WDECB 17858560              // 1M bf16 = 524288 floats (dead after k1_gemm)
#define WS_H0B   18382848              // 64K bf16 = 32768 floats
#define WS_DPART 18415616              // 8*64*1024 fp32 = 524288
// end 18939904 floats = 75.8 MB
// --- aliases inside the (dead after k3b) encB region ---
// (WcatB removed: k5 now casts Wih/Whh inline during B-staging)
#define WS_GPART 4325376               // 8*64*4096 fp32
#define WS_XINB  6422528               // 64*2112 bf16

typedef __attribute__((ext_vector_type(8))) short bf16x8;
typedef __attribute__((ext_vector_type(4))) float f32x4;

#define ASYNC_CP16(gptr, lptr) \
  __builtin_amdgcn_global_load_lds((const __attribute__((address_space(1))) void*)(gptr), \
                                   (__attribute__((address_space(3))) void*)(lptr), 16, 0, 0)

static __device__ __forceinline__ unsigned short f2bf(float f) {
    union { float f; unsigned int u; } v; v.f = f;
    unsigned int r = (v.u + 0x7fffu + ((v.u >> 16) & 1u)) >> 16;
    return (unsigned short)r;
}
static __device__ __forceinline__ float bf2f(unsigned short h) {
    union { unsigned int u; float f; } v; v.u = ((unsigned int)h) << 16;
    return v.f;
}
// fast tanh: (e^{2x}-1)/(e^{2x}+1) via hw exp + hw rcp; clamp keeps e finite
static __device__ __forceinline__ float fast_tanh(float x) {
    float cx = fminf(15.f, fmaxf(-15.f, x));
    float e = __expf(2.f * cx);
    return (e - 1.f) * __builtin_amdgcn_rcpf(e + 1.f);
}

// ---------------------------------------------------------------------------
// k_cast: fp32->bf16 for enc, Wenc, Wdec, h0. 2048 elems/block.
__global__ __launch_bounds__(256) void k_cast(const float* __restrict__ enc,
                                              const float* __restrict__ Wenc,
                                              const float* __restrict__ Wdec,
                                              const float* __restrict__ h0,
                                              unsigned short* __restrict__ encB,
                                              unsigned short* __restrict__ wencB,
                                              unsigned short* __restrict__ wdecB,
                                              unsigned short* __restrict__ h0B) {
    int bid = blockIdx.x;
    const float* src; unsigned short* dst; size_t off;
    if (bid < 16384)      { src = enc;  dst = encB;  off = (size_t)bid * 2048; }
    else if (bid < 16896) { src = Wenc; dst = wencB; off = (size_t)(bid - 16384) * 2048; }
    else if (bid < 17408) { src = Wdec; dst = wdecB; off = (size_t)(bid - 16896) * 2048; }
    else                  { src = h0;   dst = h0B;   off = (size_t)(bid - 17408) * 2048; }
    off += (size_t)threadIdx.x * 8;
    float4 v0 = *(const float4*)(src + off);
    float4 v1 = *(const float4*)(src + off + 4);
    ushort4 a; a.x = f2bf(v0.x); a.y = f2bf(v0.y); a.z = f2bf(v0.z); a.w = f2bf(v0.w);
    ushort4 b; b.x = f2bf(v1.x); b.y = f2bf(v1.y); b.z = f2bf(v1.z); b.w = f2bf(v1.w);
    *(ushort4*)(dst + off)     = a;
    *(ushort4*)(dst + off + 4) = b;
}

// ---------------------------------------------------------------------------
// k1_gemm: dpart[sp][b][g] = partial of h0B[b,:] . wdecB[g,:]  (M=64,N=1024,K=1024)
// grid (8 N-tiles, 8 K-splits); block 64x128, waves 2x2 (tile 32x64), BK=64, 2 iters.
__global__ __launch_bounds__(256) void k1_gemm(const unsigned short* __restrict__ h0B,
                                               const unsigned short* __restrict__ wdecB,
                                               float* __restrict__ dpart) {
    __shared__ short As[4096];       // 8 quads * 64 rows * 8
    __shared__ short Bs[8192];       // 8 quads * 128 rows * 8

    const int n0 = blockIdx.x * 128;
    const int sp = blockIdx.y;                    // 8 K-splits x 2 BK-iters
    const int kbeg = sp * 128;
    const int tid  = threadIdx.x;
    const int wave = tid >> 6;
    const int lane = tid & 63;
    const int wr = wave >> 1;
    const int wc = wave & 1;
    const int q4 = lane >> 4;
    const int ml = lane & 15;

    f32x4 acc[2][4];
#pragma unroll
    for (int i = 0; i < 2; ++i)
#pragma unroll
        for (int j = 0; j < 4; ++j) acc[i][j] = (f32x4){0.f, 0.f, 0.f, 0.f};

    const unsigned short* bTile = wdecB + (size_t)n0 * 1024;

    for (int kk = 0; kk < 2; ++kk) {
        int k0 = kbeg + kk * 64;
        __syncthreads();
#pragma unroll
        for (int t = 0; t < 2; ++t) {
            int q = wave * 2 + t;
            ASYNC_CP16(h0B + (size_t)lane * 1024 + k0 + q * 8, &As[(q * 64) * 8]);
        }
#pragma unroll
        for (int t = 0; t < 4; ++t) {
            int cb = t * 4 + wave;
            int q  = cb >> 1;
            int mb = (cb & 1) << 6;
            ASYNC_CP16(bTile + (size_t)(mb + lane) * 1024 + k0 + q * 8,
                       &Bs[(q * 128 + mb) * 8]);
        }
        __syncthreads();
#pragma unroll
        for (int s = 0; s < 2; ++s) {
            bf16x8 af[2], bfr[4];
#pragma unroll
            for (int i = 0; i < 2; ++i)
                af[i] = *(const bf16x8*)&As[((((s << 2) + q4) * 64) + wr * 32 + (i << 4) + ml) * 8];
#pragma unroll
            for (int j = 0; j < 4; ++j)
                bfr[j] = *(const bf16x8*)&Bs[((((s << 2) + q4) * 128) + wc * 64 + (j << 4) + ml) * 8];
#pragma unroll
            for (int i = 0; i < 2; ++i)
#pragma unroll
                for (int j = 0; j < 4; ++j)
                    acc[i][j] = __builtin_amdgcn_mfma_f32_16x16x32_bf16(af[i], bfr[j], acc[i][j], 0, 0, 0);
        }
    }
#pragma unroll
    for (int i = 0; i < 2; ++i)
#pragma unroll
        for (int j = 0; j < 4; ++j)
#pragma unroll
            for (int r = 0; r < 4; ++r) {
                int m = wr * 32 + (i << 4) + q4 * 4 + r;
                int n = n0 + wc * 64 + (j << 4) + ml;
                dpart[((size_t)sp * 64 + m) * 1024 + n] = acc[i][j][r];
            }
}

// ---------------------------------------------------------------------------
// k2: bf16 MFMA attn-score GEMM + fused fast-tanh.w_val epilogue.
// R12 (256x256, stage-ahead, vmcnt(0)-drain barriers) PASSED but regressed to
// 180 us / MfmaUtil 15.6%: __syncthreads drains vmcnt(0) each K-tile, which
// waits for the just-issued t+1 prefetch -- the overlap is structurally
// cancelled (guide m218: "8-phase-with-drain0 == 1-phase; counted-vs-drain0 =
// +38..73%"). R13: COUNTED vmcnt pipeline (T4) on the SAME verified layout:
//   prologue stages tiles 0,1 (16 loads/wave in flight);
//   per tile t: s_waitcnt vmcnt(8)   <- tile t's 8 loads done, t+1's stay
//               s_barrier             <- all waves' tile-t loads landed
//               compute (setprio 1 around MFMA cluster)
//               s_barrier             <- all reads of buf[cur] retired (WAR)
//               STAGE(t+2 -> buf[cur])
//   never drains to 0 in the loop (vmcnt(0) only at t=15).
// Math/layout/epilogue identical to R12 (HW-verified correct).
__global__ __launch_bounds__(512) void k2_scores(const unsigned short* __restrict__ encB,
                                                 const unsigned short* __restrict__ wencB,
                                                 const float* __restrict__ dpart,
                                                 const float* __restrict__ wval,
                                                 float* __restrict__ part) {
    __shared__ short As[2][16384];   // [buf][(q*256 + row)*8], q = k-octet 0..7
    __shared__ short Bs[2][16384];

    const int bid = blockIdx.x;               // 512
    const int xcd = bid & 7;                  // dispatch round-robin -> XCD id
    const int j   = bid >> 3;                 // 0..63: within-XCD issue order
    const int m0  = (xcd * 16 + (j >> 2)) * 256;  // contiguous m-chunk per XCD
    const int nb  = j & 3;                    // 4 N-tiles of one m-tile adjacent
    const int n0  = nb * 256;
    const int b   = m0 >> 9;                  // 256 | 512 -> b uniform per block
    const int tid  = threadIdx.x;
    const int wave = tid >> 6;                // 0..7
    const int lane = tid & 63;
    const int wr2 = wave >> 2;                // 0..1: rows wr2*128..+127
    const int wc2 = wave & 3;                 // 0..3: cols wc2*64..+63
    const int q4 = lane >> 4;
    const int ml = lane & 15;

    f32x4 acc[8][4];
#pragma unroll
    for (int i = 0; i < 8; ++i)
#pragma unroll
        for (int jj = 0; jj < 4; ++jj) acc[i][jj] = (f32x4){0.f, 0.f, 0.f, 0.f};

    const unsigned short* aTile = encB  + (size_t)m0 * 1024;
    const unsigned short* bTile = wencB + (size_t)n0 * 1024;

    // stage K-tile kt (k = kt*64..+63) into buffer bf: 8 loads per wave
    // (4 A + 4 B), 64 per block. Dest is wave-uniform base + lane*16B.
    auto STAGE = [&](int kt, int bf) {
        int k0 = kt * 64;
#pragma unroll
        for (int t2 = 0; t2 < 4; ++t2) {
            int c  = t2 * 8 + wave;           // 0..31
            int q  = c >> 2;                  // k-octet 0..7
            int sg = (c & 3) * 64;            // 64-row segment base
            ASYNC_CP16(aTile + (size_t)(sg + lane) * 1024 + k0 + q * 8,
                       &As[bf][(q * 256 + sg) * 8]);
            ASYNC_CP16(bTile + (size_t)(sg + lane) * 1024 + k0 + q * 8,
                       &Bs[bf][(q * 256 + sg) * 8]);
        }
    };

    STAGE(0, 0);                              // 8 loads/wave in flight
    STAGE(1, 1);                              // 16 loads/wave in flight

    for (int t = 0; t < 16; ++t) {
        const int cur = t & 1;
        // tile t's loads done; tile t+1's (8 newest) may remain in flight
        if (t < 15) asm volatile("s_waitcnt vmcnt(8)" ::: "memory");
        else        asm volatile("s_waitcnt vmcnt(0)" ::: "memory");
        __builtin_amdgcn_s_barrier();         // all waves' tile-t data in LDS
        __builtin_amdgcn_sched_barrier(0);    // no ds_read hoisted above
        bf16x8 bfr[2][4];
#pragma unroll
        for (int s = 0; s < 2; ++s)
#pragma unroll
            for (int jj = 0; jj < 4; ++jj)
                bfr[s][jj] = *(const bf16x8*)
                    &Bs[cur][(((s * 4 + q4) * 256) + wc2 * 64 + jj * 16 + ml) * 8];
        __builtin_amdgcn_s_setprio(1);
#pragma unroll
        for (int i = 0; i < 8; ++i) {
            bf16x8 a0 = *(const bf16x8*)
                &As[cur][((q4 * 256) + wr2 * 128 + i * 16 + ml) * 8];
            bf16x8 a1 = *(const bf16x8*)
                &As[cur][(((4 + q4) * 256) + wr2 * 128 + i * 16 + ml) * 8];
#pragma unroll
            for (int jj = 0; jj < 4; ++jj)
                acc[i][jj] = __builtin_amdgcn_mfma_f32_16x16x32_bf16(a0, bfr[0][jj], acc[i][jj], 0, 0, 0);
#pragma unroll
            for (int jj = 0; jj < 4; ++jj)
                acc[i][jj] = __builtin_amdgcn_mfma_f32_16x16x32_bf16(a1, bfr[1][jj], acc[i][jj], 0, 0, 0);
        }
        __builtin_amdgcn_s_setprio(0);
        __builtin_amdgcn_sched_barrier(0);    // keep reads/MFMAs above barrier
        __builtin_amdgcn_s_barrier();         // all reads of buf[cur] retired
        if (t < 14) STAGE(t + 2, cur);        // refill the buffer just freed
    }

    // epilogue: dec_proj = sum of 8 k1 splits; tanh()*wval row-reduced
    float dpv[4], wvv[4];
#pragma unroll
    for (int jj = 0; jj < 4; ++jj) {
        int n = n0 + wc2 * 64 + jj * 16 + ml;
        float d = 0.f;
#pragma unroll
        for (int sp = 0; sp < 8; ++sp) d += dpart[((size_t)sp * 64 + b) * 1024 + n];
        dpv[jj] = d;
        wvv[jj] = wval[n];
    }
    float* rsum = (float*)As;                 // [4 n-slices][256 rows] = 4 KB
#pragma unroll
    for (int i = 0; i < 8; ++i) {
#pragma unroll
        for (int r = 0; r < 4; ++r) {
            float p = 0.f;
#pragma unroll
            for (int jj = 0; jj < 4; ++jj) p += fast_tanh(acc[i][jj][r] + dpv[jj]) * wvv[jj];
            p += __shfl_xor(p, 1);
            p += __shfl_xor(p, 2);
            p += __shfl_xor(p, 4);
            p += __shfl_xor(p, 8);
            if (ml == 0) rsum[wc2 * 256 + wr2 * 128 + i * 16 + q4 * 4 + r] = p;
        }
    }
    __syncthreads();
    if (tid < 256)
        part[(size_t)nb * Mn + m0 + tid] =
            rsum[tid] + rsum[256 + tid] + rsum[512 + tid] + rsum[768 + tid];
}

// ---------------------------------------------------------------------------
__device__ __forceinline__ float block_sum256(float v, float* red, int tid) {
#pragma unroll
    for (int off = 1; off < 64; off <<= 1) v += __shfl_xor(v, off);
    if ((tid & 63) == 0) red[tid >> 6] = v;
    __syncthreads();
    v = red[0] + red[1] + red[2] + red[3];
    __syncthreads();
    return v;
}

// k3a: sum 4 partial slices (k2 has 4 N-tiles of 256) -> softmax -> attn_w
__global__ __launch_bounds__(256) void k3a_softmax(const float* __restrict__ part,
                                                   float* __restrict__ wts,
                                                   float* __restrict__ out) {
    int b = blockIdx.x;
    int tid = threadIdx.x;
    __shared__ float red[8];
    int s0 = tid, s1 = tid + 256;
    float v0 = 0.f, v1 = 0.f;
#pragma unroll
    for (int nb = 0; nb < 4; ++nb) {
        v0 += part[(size_t)nb * Mn + b * 512 + s0];
        v1 += part[(size_t)nb * Mn + b * 512 + s1];
    }
    float mx = fmaxf(v0, v1);
#pragma unroll
    for (int off = 1; off < 64; off <<= 1) mx = fmaxf(mx, __shfl_xor(mx, off));
    if ((tid & 63) == 0) red[tid >> 6] = mx;
    __syncthreads();
    mx = fmaxf(fmaxf(red[0], red[1]), fmaxf(red[2], red[3]));
    __syncthreads();
    float e0 = __expf(v0 - mx), e1 = __expf(v1 - mx);
    float sm = block_sum256(e0 + e1, red, tid);
    float inv = 1.0f / sm;
    float w0 = e0 * inv, w1 = e1 * inv;
    wts[b * 512 + s0] = w0;
    wts[b * 512 + s1] = w1;
    out[OUT_AW + b * 512 + s0] = w0;
    out[OUT_AW + b * 512 + s1] = w1;
}

// k3b: ctxp[sc][b][h] = sum_{s in 64-chunk sc} w[b,s] * encB[b,s,h]  (8 S-chunks)
// Widened loads (G13): 8 B/lane (uint2 = 4 bf16); s-dim split 2-way across
// thread halves, combined via 2 KB LDS. Output layout ctxp[8][64][1024].
__global__ __launch_bounds__(256) void k3b_context(const unsigned short* __restrict__ encB,
                                                   const float* __restrict__ wts,
                                                   float* __restrict__ ctxp) {
    int b  = blockIdx.y;
    int sc = blockIdx.x >> 1;                        // 0..7
    int hh = blockIdx.x & 1;                         // h half
    int tid = threadIdx.x;
    int sr = tid >> 7;                               // 0..1: s parity
    int cl = tid & 127;                              // 0..127
    int hc = hh * 512 + cl * 4;                      // 4-col group
    const unsigned short* e = encB + (size_t)b * Sn * Hn + (size_t)sc * 64 * Hn + hc;
    const float* w = wts + b * 512 + sc * 64;
    float a0 = 0.f, a1 = 0.f, a2 = 0.f, a3 = 0.f;
#pragma unroll 8
    for (int s = sr; s < 64; s += 2) {
        uint2 p = *(const uint2*)(e + (size_t)s * 1024);
        float ws = w[s];
        a0 += ws * bf2f((unsigned short)(p.x & 0xffffu));
        a1 += ws * bf2f((unsigned short)(p.x >> 16));
        a2 += ws * bf2f((unsigned short)(p.y & 0xffffu));
        a3 += ws * bf2f((unsigned short)(p.y >> 16));
    }
    __shared__ float lds[512];                       // 2 KB
    if (sr == 1) *(float4*)&lds[cl * 4] = (float4){a0, a1, a2, a3};
    __syncthreads();
    if (sr == 0) {
        float4 o = *(const float4*)&lds[cl * 4];
        o.x += a0; o.y += a1; o.z += a2; o.w += a3;
        *(float4*)(ctxp + ((size_t)sc * 64 + b) * 1024 + hc) = o;
    }
}

// k4: ctx assembled in LDS from 8 ctxp chunks; sim[b,e'] = W_gate . (ctx . events^T).
// FUSED k_xinB: emits the bf16 LSTM input row xinB[b] directly.
__global__ __launch_bounds__(256) void k4_sim(const float* __restrict__ ctxp,
                                              const float* __restrict__ events,
                                              const float* __restrict__ Wg,
                                              const float* __restrict__ x,
                                              const float* __restrict__ h0,
                                              float* __restrict__ out,
                                              unsigned short* __restrict__ xinB) {
    int b = blockIdx.x;
    int tid = threadIdx.x, wv = tid >> 6, lane = tid & 63;
    __shared__ float cl[1024];
    __shared__ float tmp[16];
    unsigned short* xrow = xinB + (size_t)b * KP;
#pragma unroll
    for (int i = 0; i < 4; ++i) {
        int h = tid + i * 256;
        float v = 0.f;
#pragma unroll
        for (int sc = 0; sc < 8; ++sc) v += ctxp[((size_t)sc * 64 + b) * 1024 + h];
        cl[h] = v;
        xrow[h] = f2bf(v);                       // xin[0:1024] = ctx
        xrow[1035 + h] = f2bf(h0[b * 1024 + h]); // xin[1035:2059] = h0
    }
    // xin tail: x at 1034, zero pad 2059..2111
    if (tid == 0) xrow[1034] = f2bf(x[b]);
    if (tid < 53) xrow[2059 + tid] = 0;
    __syncthreads();
    for (int e = wv; e < 10; e += 4) {
        const float* ev = events + e * 1024;
        float a = 0.f;
#pragma unroll
        for (int kk = 0; kk < 1024; kk += 64) a += cl[kk + lane] * ev[kk + lane];
#pragma unroll
        for (int off = 1; off < 64; off <<= 1) a += __shfl_xor(a, off);
        if (lane == 0) tmp[e] = a;
    }
    __syncthreads();
    if (tid < 10) {
        float s2 = 0.f;
#pragma unroll
        for (int e = 0; e < 10; ++e) s2 += Wg[tid * 10 + e] * tmp[e];
        out[OUT_SIM + b * 10 + tid] = s2;
        xrow[1024 + tid] = f2bf(s2);             // xin[1024:1034] = sim
    }
}

// ---------------------------------------------------------------------------
// k5_gemm: G[64,4096] = xinB[64,KP] . Wcat[4096,KP]^T  with split-K 8.
// FUSED k_castW: Wcat gathered + f2bf-cast inline during B-staging.
__global__ __launch_bounds__(256) void k5_gemm(const unsigned short* __restrict__ xinB,
                                               const float* __restrict__ Wih,
                                               const float* __restrict__ Whh,
                                               float* __restrict__ gpart) {
    __shared__ short As[4096];
    __shared__ short Bs[8192];

    const int n0 = blockIdx.x * 128;
    const int sp = blockIdx.y;
    const int kbeg   = (sp == 0) ? 0 : (5 + (sp - 1) * 4) * 64;
    const int ksteps = (sp == 0) ? 5 : 4;
    const int tid  = threadIdx.x;
    const int wave = tid >> 6;
    const int lane = tid & 63;
    const int wr = wave >> 1;
    const int wc = wave & 1;
    const int q4 = lane >> 4;
    const int ml = lane & 15;

    f32x4 acc[2][4];
#pragma unroll
    for (int i = 0; i < 2; ++i)
#pragma unroll
        for (int j = 0; j < 4; ++j) acc[i][j] = (f32x4){0.f, 0.f, 0.f, 0.f};

    for (int kk = 0; kk < ksteps; ++kk) {
        int k0 = kbeg + kk * 64;
        __syncthreads();
#pragma unroll
        for (int t = 0; t < 2; ++t) {
            int q = wave * 2 + t;
            ASYNC_CP16(xinB + (size_t)lane * KP + k0 + q * 8, &As[(q * 64) * 8]);
        }
        // B staging: inline cast from Wih/Whh (replaces WcatB ASYNC_CP16)
#pragma unroll
        for (int t = 0; t < 4; ++t) {
            int cb = t * 4 + wave;
            int q  = cb >> 1;
            int mb = (cb & 1) << 6;
            int g  = n0 + mb + lane;          // gate row (per-lane)
            int kq = k0 + q * 8;              // wave-uniform col base
            const float* rih = Wih + (size_t)g * 1035;
            const float* rhh = Whh + (size_t)g * 1024 - 1035;   // index by k directly
            union { unsigned short us[8]; bf16x8 v; } pk;
#pragma unroll
            for (int e2 = 0; e2 < 8; ++e2) {
                int k = kq + e2;              // wave-uniform -> scalar branch
                float vv;
                if (k < 1035)      vv = rih[k];
                else if (k < 2059) vv = rhh[k];
                else               vv = 0.f;
                pk.us[e2] = f2bf(vv);
            }
            *(bf16x8*)&Bs[(q * 128 + mb + lane) * 8] = pk.v;
        }
        __syncthreads();
#pragma unroll
        for (int s = 0; s < 2; ++s) {
            bf16x8 af[2], bfr[4];
#pragma unroll
            for (int i = 0; i < 2; ++i)
                af[i] = *(const bf16x8*)&As[((((s << 2) + q4) * 64) + wr * 32 + (i << 4) + ml) * 8];
#pragma unroll
            for (int j = 0; j < 4; ++j)
                bfr[j] = *(const bf16x8*)&Bs[((((s << 2) + q4) * 128) + wc * 64 + (j << 4) + ml) * 8];
#pragma unroll
            for (int i = 0; i < 2; ++i)
#pragma unroll
                for (int j = 0; j < 4; ++j)
                    acc[i][j] = __builtin_amdgcn_mfma_f32_16x16x32_bf16(af[i], bfr[j], acc[i][j], 0, 0, 0);
        }
    }
#pragma unroll
    for (int i = 0; i < 2; ++i)
#pragma unroll
        for (int j = 0; j < 4; ++j)
#pragma unroll
            for (int r = 0; r < 4; ++r) {
                int m = wr * 32 + (i << 4) + q4 * 4 + r;
                int n = n0 + wc * 64 + (j << 4) + ml;
                gpart[((size_t)sp * 64 + m) * 4096 + n] = acc[i][j][r];
            }
}

// k56: gates = sum_sp gpart + biases -> LSTM cell -> h,c; then fused LayerNorm+fin.
__global__ __launch_bounds__(256) void k56_lstm_ln(const float* __restrict__ gpart,
                                                   const float* __restrict__ bih,
                                                   const float* __restrict__ bhh,
                                                   const float* __restrict__ c0,
                                                   const float* __restrict__ lng,
                                                   const float* __restrict__ lnb,
                                                   const float* __restrict__ Wfin,
                                                   const float* __restrict__ bfin,
                                                   float* __restrict__ out) {
    int b = blockIdx.x, tid = threadIdx.x;
    __shared__ float red[8];
    float hn[4];
#pragma unroll
    for (int r = 0; r < 4; ++r) {
        int u = tid + (r << 8);
        float g[4];
#pragma unroll
        for (int gt = 0; gt < 4; ++gt) {
            int rr = gt * 1024 + u;
            float a = bih[rr] + bhh[rr];
#pragma unroll
            for (int sp = 0; sp < 8; ++sp)
                a += gpart[((size_t)sp * 64 + b) * 4096 + rr];
            g[gt] = a;
        }
        float cp = c0[b * 1024 + u];
        float si = 1.f / (1.f + __expf(-g[0]));
        float sf = 1.f / (1.f + __expf(-g[1]));
        float so = 1.f / (1.f + __expf(-g[3]));
        float cn = sf * cp + si * tanhf(g[2]);
        hn[r] = so * tanhf(cn);
        out[OUT_H + b * 1024 + u] = hn[r];
        out[OUT_C + b * 1024 + u] = cn;
    }
    // LayerNorm + final dot
    float mu = block_sum256(hn[0] + hn[1] + hn[2] + hn[3], red, tid) * (1.f / 1024.f);
    float d0 = hn[0] - mu, d1 = hn[1] - mu, d2 = hn[2] - mu, d3 = hn[3] - mu;
    float var = block_sum256(d0 * d0 + d1 * d1 + d2 * d2 + d3 * d3, red, tid) * (1.f / 1024.f);
    float rstd = rsqrtf(var + 1e-5f);
    float acc = (d0 * rstd * lng[tid]       + lnb[tid])       * Wfin[tid]
              + (d1 * rstd * lng[tid + 256] + lnb[tid + 256]) * Wfin[tid + 256]
              + (d2 * rstd * lng[tid + 512] + lnb[tid + 512]) * Wfin[tid + 512]
              + (d3 * rstd * lng[tid + 768] + lnb[tid + 768]) * Wfin[tid + 768];
    acc = block_sum256(acc, red, tid);
    if (tid == 0) out[OUT_FIN + b] = acc + bfin[0];
}

// ---------------------------------------------------------------------------
extern "C" void kernel_launch(void* const* d_in, const int* in_sizes, int n_in,
                              void* d_out, int out_size, void* d_ws, size_t ws_size,
                              hipStream_t stream) {
    (void)in_sizes; (void)n_in; (void)out_size; (void)ws_size;
    const float* x    = (const float*)d_in[0];
    const float* h0   = (const float*)d_in[1];
    const float* c0   = (const float*)d_in[2];
    const float* enc  = (const float*)d_in[3];
    const float* Wenc = (const float*)d_in[4];
    const float* Wdec = (const float*)d_in[5];
    const float* wval = (const float*)d_in[6];
    const float* Wg   = (const float*)d_in[7];
    const float* ev   = (const float*)d_in[8];
    const float* Wih  = (const float*)d_in[9];
    const float* Whh  = (const float*)d_in[10];
    const float* bih  = (const float*)d_in[11];
    const float* bhh  = (const float*)d_in[12];
    const float* lng  = (const float*)d_in[13];
    const float* lnb  = (const float*)d_in[14];
    const float* Wfin = (const float*)d_in[15];
    const float* bfin = (const float*)d_in[16];

    float* out  = (float*)d_out;
    float* ws   = (float*)d_ws;
    unsigned short* encB  = (unsigned short*)(ws + WS_ENCB);
    unsigned short* wencB = (unsigned short*)(ws + WS_WENCB);
    unsigned short* wdecB = (unsigned short*)(ws + WS_WDECB);
    unsigned short* h0B   = (unsigned short*)(ws + WS_H0B);
    float* dpart = ws + WS_DPART;
    float* wts   = ws + WS_WTS;
    float* part  = ws + WS_PART;
    float* ctxp  = ws + WS_CTXP;                                // alias over part (dead after k3a)
    float* gpart = ws + WS_GPART;                               // alias encB (dead after k3b)
    unsigned short* xinB  = (unsigned short*)(ws + WS_XINB);    // alias encB

    k_cast     <<<17440, 256, 0, stream>>>(enc, Wenc, Wdec, h0, encB, wencB, wdecB, h0B);
    k1_gemm    <<<dim3(8, 8), 256, 0, stream>>>(h0B, wdecB, dpart);
    k2_scores  <<<512, 512, 0, stream>>>(encB, wencB, dpart, wval, part);
    k3a_softmax<<<64, 256, 0, stream>>>(part, wts, out);
    k3b_context<<<dim3(16, 64), 256, 0, stream>>>(encB, wts, ctxp);
    // encB region dead past k3b -> safe for LSTM buffers (k4 writes xinB there)
    k4_sim     <<<64, 256, 0, stream>>>(ctxp, ev, Wg, x, h0, out, xinB);
    k5_gemm    <<<dim3(32, 8), 256, 0, stream>>>(xinB, Wih, Whh, gpart);
    k56_lstm_ln<<<64, 256, 0, stream>>>(gpart, bih, bhh, c0, lng, lnb, Wfin, bfin, out);
}

// Round 17
// 452.333 us; speedup vs baseline: 1.0573x; 1.0377x over previous
//
#include <hip/hip_runtime.h>
#include <math.h>

// Problem dims
#define Bn 64
#define Sn 512
#define Hn 1024
#define En 10
#define Mn (Bn*Sn)          // 32768 rows of the attention GEMM
#define KIN 1035            // H + E + 1  (xin length)
#define KP  2112            // padded LSTM K: 2059 -> 33*64

// d_out flat offsets (floats): fin(64), h_new(65536), c_new(65536), attn_w(32768), sim(640)
#define OUT_FIN 0
#define OUT_H   64
#define OUT_C   65600
#define OUT_AW  131136
#define OUT_SIM 163904

// d_ws offsets (floats)
#define WS_ENCB  0                     // 32M bf16; dead after k3ab -> LSTM aliases
#define WS_WENCB 16777216              // 1M bf16
#define WS_WTS   17301504              // (unused since R17 k3a+k3b fusion)
#define WS_PART  17334272              // 8*32768 fp32 (k2 partials; READ by k3ab)
#define WS_WDECB 17858560              // 1M bf16 = 524288 floats (dead after k1_gemm)
#define WS_CTXP  17858560              // 8*64*1024 fp32, alias over WDECB.
                                       // NOT over PART anymore: fused k3ab still
                                       // READS part while writing ctxp -> the old
                                       // alias would be a cross-block race.
#define WS_H0B   18382848              // 64K bf16 = 32768 floats
#define WS_DPART 18415616              // 8*64*1024 fp32 = 524288
// end 18939904 floats = 75.8 MB
// --- aliases inside the (dead after k3ab) encB region ---
// (WcatB removed: k5 now casts Wih/Whh inline during B-staging)
#define WS_GPART 4325376               // 8*64*4096 fp32
#define WS_XINB  6422528               // 64*2112 bf16

typedef __attribute__((ext_vector_type(8))) short bf16x8;
typedef __attribute__((ext_vector_type(4))) float f32x4;

#define ASYNC_CP16(gptr, lptr) \
  __builtin_amdgcn_global_load_lds((const __attribute__((address_space(1))) void*)(gptr), \
                                   (__attribute__((address_space(3))) void*)(lptr), 16, 0, 0)

static __device__ __forceinline__ unsigned short f2bf(float f) {
    union { float f; unsigned int u; } v; v.f = f;
    unsigned int r = (v.u + 0x7fffu + ((v.u >> 16) & 1u)) >> 16;
    return (unsigned short)r;
}
static __device__ __forceinline__ float bf2f(unsigned short h) {
    union { unsigned int u; float f; } v; v.u = ((unsigned int)h) << 16;
    return v.f;
}
// fast tanh: (e^{2x}-1)/(e^{2x}+1) via hw exp + hw rcp; clamp keeps e finite
static __device__ __forceinline__ float fast_tanh(float x) {
    float cx = fminf(15.f, fmaxf(-15.f, x));
    float e = __expf(2.f * cx);
    return (e - 1.f) * __builtin_amdgcn_rcpf(e + 1.f);
}

// ---------------------------------------------------------------------------
// k_cast: fp32->bf16 for enc, Wenc, Wdec, h0. 2048 elems/block.
// R14: single 16B store per thread (bf16x8) instead of 2x 8B ushort4.
__global__ __launch_bounds__(256) void k_cast(const float* __restrict__ enc,
                                              const float* __restrict__ Wenc,
                                              const float* __restrict__ Wdec,
                                              const float* __restrict__ h0,
                                              unsigned short* __restrict__ encB,
                                              unsigned short* __restrict__ wencB,
                                              unsigned short* __restrict__ wdecB,
                                              unsigned short* __restrict__ h0B) {
    int bid = blockIdx.x;
    const float* src; unsigned short* dst; size_t off;
    if (bid < 16384)      { src = enc;  dst = encB;  off = (size_t)bid * 2048; }
    else if (bid < 16896) { src = Wenc; dst = wencB; off = (size_t)(bid - 16384) * 2048; }
    else if (bid < 17408) { src = Wdec; dst = wdecB; off = (size_t)(bid - 16896) * 2048; }
    else                  { src = h0;   dst = h0B;   off = (size_t)(bid - 17408) * 2048; }
    off += (size_t)threadIdx.x * 8;
    float4 v0 = *(const float4*)(src + off);
    float4 v1 = *(const float4*)(src + off + 4);
    union { unsigned short us[8]; bf16x8 v; } pk;
    pk.us[0] = f2bf(v0.x); pk.us[1] = f2bf(v0.y); pk.us[2] = f2bf(v0.z); pk.us[3] = f2bf(v0.w);
    pk.us[4] = f2bf(v1.x); pk.us[5] = f2bf(v1.y); pk.us[6] = f2bf(v1.z); pk.us[7] = f2bf(v1.w);
    *(bf16x8*)(dst + off) = pk.v;    // off*2 bytes: tid*16 -> 16B aligned
}

// ---------------------------------------------------------------------------
// k1_gemm: dpart[sp][b][g] = partial of h0B[b,:] . wdecB[g,:]  (M=64,N=1024,K=1024)
// grid (8 N-tiles, 8 K-splits); block 64x128, waves 2x2 (tile 32x64), BK=64, 2 iters.
__global__ __launch_bounds__(256) void k1_gemm(const unsigned short* __restrict__ h0B,
                                               const unsigned short* __restrict__ wdecB,
                                               float* __restrict__ dpart) {
    __shared__ short As[4096];       // 8 quads * 64 rows * 8
    __shared__ short Bs[8192];       // 8 quads * 128 rows * 8

    const int n0 = blockIdx.x * 128;
    const int sp = blockIdx.y;                    // 8 K-splits x 2 BK-iters
    const int kbeg = sp * 128;
    const int tid  = threadIdx.x;
    const int wave = tid >> 6;
    const int lane = tid & 63;
    const int wr = wave >> 1;
    const int wc = wave & 1;
    const int q4 = lane >> 4;
    const int ml = lane & 15;

    f32x4 acc[2][4];
#pragma unroll
    for (int i = 0; i < 2; ++i)
#pragma unroll
        for (int j = 0; j < 4; ++j) acc[i][j] = (f32x4){0.f, 0.f, 0.f, 0.f};

    const unsigned short* bTile = wdecB + (size_t)n0 * 1024;

    for (int kk = 0; kk < 2; ++kk) {
        int k0 = kbeg + kk * 64;
        __syncthreads();
#pragma unroll
        for (int t = 0; t < 2; ++t) {
            int q = wave * 2 + t;
            ASYNC_CP16(h0B + (size_t)lane * 1024 + k0 + q * 8, &As[(q * 64) * 8]);
        }
#pragma unroll
        for (int t = 0; t < 4; ++t) {
            int cb = t * 4 + wave;
            int q  = cb >> 1;
            int mb = (cb & 1) << 6;
            ASYNC_CP16(bTile + (size_t)(mb + lane) * 1024 + k0 + q * 8,
                       &Bs[(q * 128 + mb) * 8]);
        }
        __syncthreads();
#pragma unroll
        for (int s = 0; s < 2; ++s) {
            bf16x8 af[2], bfr[4];
#pragma unroll
            for (int i = 0; i < 2; ++i)
                af[i] = *(const bf16x8*)&As[((((s << 2) + q4) * 64) + wr * 32 + (i << 4) + ml) * 8];
#pragma unroll
            for (int j = 0; j < 4; ++j)
                bfr[j] = *(const bf16x8*)&Bs[((((s << 2) + q4) * 128) + wc * 64 + (j << 4) + ml) * 8];
#pragma unroll
            for (int i = 0; i < 2; ++i)
#pragma unroll
                for (int j = 0; j < 4; ++j)
                    acc[i][j] = __builtin_amdgcn_mfma_f32_16x16x32_bf16(af[i], bfr[j], acc[i][j], 0, 0, 0);
        }
    }
#pragma unroll
    for (int i = 0; i < 2; ++i)
#pragma unroll
        for (int j = 0; j < 4; ++j)
#pragma unroll
            for (int r = 0; r < 4; ++r) {
                int m = wr * 32 + (i << 4) + q4 * 4 + r;
                int n = n0 + wc * 64 + (j << 4) + ml;
                dpart[((size_t)sp * 64 + m) * 1024 + n] = acc[i][j][r];
            }
}

// ---------------------------------------------------------------------------
// k2: bf16 MFMA attn-score GEMM + fused fast-tanh.w_val epilogue.
// R9 known-good structure (152 us): 128x128 tile, BK=64, 2-barrier K-loop,
// 4 blocks/CU cross-block overlap. Structural attempts measured and rejected:
//   R12 256^2 stage-ahead + drain0 barriers: 180 us (drain cancels prefetch)
//   R13 256^2 + counted vmcnt(8), coarse phases: 172 us (m196: coarse
//       phase-split WITHOUT fine ds_read||load||MFMA interleave hurts)
// __launch_bounds__(512, 4) -- NOT 8 (R8: min-waves=8 caps allocator at 64
// VGPR and spills acc to scratch). Grid 2048 1-D, XCD-chunked swizzle (T1).
__global__ __launch_bounds__(512, 4) void k2_scores(const unsigned short* __restrict__ encB,
                                                    const unsigned short* __restrict__ wencB,
                                                    const float* __restrict__ dpart,
                                                    const float* __restrict__ wval,
                                                    float* __restrict__ part) {
    __shared__ short As[8192];       // 8 quads * 128 rows * 8 bf16 = 16 KB
    __shared__ short Bs[8192];       // 16 KB  (rsum aliases As after the loop)

    const int bid = blockIdx.x;               // 2048
    const int xcd = bid & 7;                  // dispatch round-robin -> XCD id
    const int j   = bid >> 3;                 // 0..255: within-XCD issue order
    const int m0  = (xcd * 32 + (j >> 3)) * 128;  // contiguous m-chunk per XCD
    const int nb  = j & 7;                    // 8 N-tiles of one m-tile adjacent
    const int n0  = nb * 128;
    const int b   = m0 >> 9;                  // 128 | 512 -> b uniform per block
    const int tid  = threadIdx.x;
    const int wave = tid >> 6;                // 0..7
    const int lane = tid & 63;
    const int wr = wave >> 1;                 // 0..3: rows wr*32..+31
    const int wc = wave & 1;                  // cols wc*64..+63
    const int q4 = lane >> 4;
    const int ml = lane & 15;

    f32x4 acc[2][4];
#pragma unroll
    for (int i = 0; i < 2; ++i)
#pragma unroll
        for (int j2 = 0; j2 < 4; ++j2) acc[i][j2] = (f32x4){0.f, 0.f, 0.f, 0.f};

    const unsigned short* aTile = encB  + (size_t)m0 * 1024;
    const unsigned short* bTile = wencB + (size_t)n0 * 1024;

    for (int k0 = 0; k0 < 1024; k0 += 64) {      // 16 iterations
        __syncthreads();
        // 32 wave-loads: A = 16 (8 quads x 2 row-halves), B = 16. 4 per wave.
#pragma unroll
        for (int t = 0; t < 4; ++t) {
            int c = t * 8 + wave;
            if (c < 16) {
                int q  = c >> 1;
                int mb = (c & 1) << 6;
                ASYNC_CP16(aTile + (size_t)(mb + lane) * 1024 + k0 + q * 8,
                           &As[(q * 128 + mb) * 8]);
            } else {
                int c2 = c - 16;
                int q  = c2 >> 1;
                int mb = (c2 & 1) << 6;
                ASYNC_CP16(bTile + (size_t)(mb + lane) * 1024 + k0 + q * 8,
                           &Bs[(q * 128 + mb) * 8]);
            }
        }
        __syncthreads();
#pragma unroll
        for (int s = 0; s < 2; ++s) {
            bf16x8 af[2], bfr[4];
            int q = (s << 2) + q4;               // 8 quads of 8 cols
#pragma unroll
            for (int i = 0; i < 2; ++i)
                af[i] = *(const bf16x8*)&As[((q * 128) + wr * 32 + (i << 4) + ml) * 8];
#pragma unroll
            for (int j2 = 0; j2 < 4; ++j2)
                bfr[j2] = *(const bf16x8*)&Bs[((q * 128) + wc * 64 + (j2 << 4) + ml) * 8];
#pragma unroll
            for (int i = 0; i < 2; ++i)
#pragma unroll
                for (int j2 = 0; j2 < 4; ++j2)
                    acc[i][j2] = __builtin_amdgcn_mfma_f32_16x16x32_bf16(af[i], bfr[j2], acc[i][j2], 0, 0, 0);
        }
    }

    // epilogue: dec_proj = sum of 8 k1 splits; rows of tanh()*wval reduced over 128 cols
    float dpv[4], wvv[4];
#pragma unroll
    for (int j2 = 0; j2 < 4; ++j2) {
        int n = n0 + wc * 64 + (j2 << 4) + ml;
        float d = 0.f;
#pragma unroll
        for (int sp = 0; sp < 8; ++sp) d += dpart[((size_t)sp * 64 + b) * 1024 + n];
        dpv[j2] = d;
        wvv[j2] = wval[n];
    }
    __syncthreads();                 // all LDS reads done -> reuse As as rsum
    float* rsum = (float*)As;        // [2][128]
#pragma unroll
    for (int i = 0; i < 2; ++i) {
#pragma unroll
        for (int r = 0; r < 4; ++r) {
            float p = 0.f;
#pragma unroll
            for (int j2 = 0; j2 < 4; ++j2) p += fast_tanh(acc[i][j2][r] + dpv[j2]) * wvv[j2];
            p += __shfl_xor(p, 1);
            p += __shfl_xor(p, 2);
            p += __shfl_xor(p, 4);
            p += __shfl_xor(p, 8);
            if (ml == 0) rsum[wc * 128 + wr * 32 + (i << 4) + q4 * 4 + r] = p;
        }
    }
    __syncthreads();
    if (tid < 128)
        part[(size_t)nb * Mn + m0 + tid] = rsum[tid] + rsum[128 + tid];
}

// ---------------------------------------------------------------------------
__device__ __forceinline__ float block_sum256(float v, float* red, int tid) {
#pragma unroll
    for (int off = 1; off < 64; off <<= 1) v += __shfl_xor(v, off);
    if ((tid & 63) == 0) red[tid >> 6] = v;
    __syncthreads();
    v = red[0] + red[1] + red[2] + red[3];
    __syncthreads();
    return v;
}

// k3ab: FUSED softmax + context (was k3a + k3b). R17: the non-k2 tail is a
// stable ~299 us across all successful benches vs ~80 us roofline -> launch
// gaps dominate; cut a dispatch. Each of the 16 blocks per batch row
// recomputes the row softmax from part inline (k3a code verbatim; 16 KB
// L2-hot reads/block, part = 1 MB L2-resident -> ~2-4 us total overhead)
// and keeps the weights in LDS -- kills the k3a launch and the wts global
// round-trip. blockIdx.x == 0 writes attn_weight to out.
// ctxp is RELOCATED to the dead-wdecB region: the old ctxp==part alias
// would now be a cross-block write-read race (sc<4 blocks write ctxp over
// part cells other blocks still read for their softmax).
__global__ __launch_bounds__(256) void k3ab_context(const unsigned short* __restrict__ encB,
                                                    const float* __restrict__ part,
                                                    float* __restrict__ ctxp,
                                                    float* __restrict__ out) {
    int b  = blockIdx.y;
    int sc = blockIdx.x >> 1;                        // 0..7
    int hh = blockIdx.x & 1;                         // h half
    int tid = threadIdx.x;
    __shared__ float red[8];
    __shared__ float wrow[512];
    __shared__ float lds[512];                       // 2 KB combine buffer

    // --- row softmax (verbatim k3a logic) ---
    int s0 = tid, s1 = tid + 256;
    float v0 = 0.f, v1 = 0.f;
#pragma unroll
    for (int nb = 0; nb < 8; ++nb) {
        v0 += part[(size_t)nb * Mn + b * 512 + s0];
        v1 += part[(size_t)nb * Mn + b * 512 + s1];
    }
    float mx = fmaxf(v0, v1);
#pragma unroll
    for (int off = 1; off < 64; off <<= 1) mx = fmaxf(mx, __shfl_xor(mx, off));
    if ((tid & 63) == 0) red[tid >> 6] = mx;
    __syncthreads();
    mx = fmaxf(fmaxf(red[0], red[1]), fmaxf(red[2], red[3]));
    __syncthreads();
    float e0 = __expf(v0 - mx), e1 = __expf(v1 - mx);
    float sm = block_sum256(e0 + e1, red, tid);
    float inv = 1.0f / sm;
    float w0 = e0 * inv, w1 = e1 * inv;
    wrow[s0] = w0;
    wrow[s1] = w1;
    if (blockIdx.x == 0) {                           // one writer per row
        out[OUT_AW + b * 512 + s0] = w0;
        out[OUT_AW + b * 512 + s1] = w1;
    }
    __syncthreads();

    // --- weighted encB sum for this (sc, hh) chunk (k3b body, w from LDS) ---
    int sr = tid >> 7;                               // 0..1: s parity
    int cl = tid & 127;                              // 0..127
    int hc = hh * 512 + cl * 4;                      // 4-col group
    const unsigned short* e = encB + (size_t)b * Sn * Hn + (size_t)sc * 64 * Hn + hc;
    const float* w = wrow + sc * 64;
    float a0 = 0.f, a1 = 0.f, a2 = 0.f, a3 = 0.f;
#pragma unroll 8
    for (int s = sr; s < 64; s += 2) {
        uint2 p = *(const uint2*)(e + (size_t)s * 1024);
        float ws = w[s];
        a0 += ws * bf2f((unsigned short)(p.x & 0xffffu));
        a1 += ws * bf2f((unsigned short)(p.x >> 16));
        a2 += ws * bf2f((unsigned short)(p.y & 0xffffu));
        a3 += ws * bf2f((unsigned short)(p.y >> 16));
    }
    if (sr == 1) *(float4*)&lds[cl * 4] = (float4){a0, a1, a2, a3};
    __syncthreads();
    if (sr == 0) {
        float4 o = *(const float4*)&lds[cl * 4];
        o.x += a0; o.y += a1; o.z += a2; o.w += a3;
        *(float4*)(ctxp + ((size_t)sc * 64 + b) * 1024 + hc) = o;
    }
}

// k4: ctx assembled in LDS from 8 ctxp chunks; sim[b,e'] = W_gate . (ctx . events^T).
// FUSED k_xinB: emits the bf16 LSTM input row xinB[b] directly.
__global__ __launch_bounds__(256) void k4_sim(const float* __restrict__ ctxp,
                                              const float* __restrict__ events,
                                              const float* __restrict__ Wg,
                                              const float* __restrict__ x,
                                              const float* __restrict__ h0,
                                              float* __restrict__ out,
                                              unsigned short* __restrict__ xinB) {
    int b = blockIdx.x;
    int tid = threadIdx.x, wv = tid >> 6, lane = tid & 63;
    __shared__ float cl[1024];
    __shared__ float tmp[16];
    unsigned short* xrow = xinB + (size_t)b * KP;
#pragma unroll
    for (int i = 0; i < 4; ++i) {
        int h = tid + i * 256;
        float v = 0.f;
#pragma unroll
        for (int sc = 0; sc < 8; ++sc) v += ctxp[((size_t)sc * 64 + b) * 1024 + h];
        cl[h] = v;
        xrow[h] = f2bf(v);                       // xin[0:1024] = ctx
        xrow[1035 + h] = f2bf(h0[b * 1024 + h]); // xin[1035:2059] = h0
    }
    // xin tail: x at 1034, zero pad 2059..2111
    if (tid == 0) xrow[1034] = f2bf(x[b]);
    if (tid < 53) xrow[2059 + tid] = 0;
    __syncthreads();
    for (int e = wv; e < 10; e += 4) {
        const float* ev = events + e * 1024;
        float a = 0.f;
#pragma unroll
        for (int kk = 0; kk < 1024; kk += 64) a += cl[kk + lane] * ev[kk + lane];
#pragma unroll
        for (int off = 1; off < 64; off <<= 1) a += __shfl_xor(a, off);
        if (lane == 0) tmp[e] = a;
    }
    __syncthreads();
    if (tid < 10) {
        float s2 = 0.f;
#pragma unroll
        for (int e = 0; e < 10; ++e) s2 += Wg[tid * 10 + e] * tmp[e];
        out[OUT_SIM + b * 10 + tid] = s2;
        xrow[1024 + tid] = f2bf(s2);             // xin[1024:1034] = sim
    }
}

// ---------------------------------------------------------------------------
// k5_gemm: G[64,4096] = xinB[64,KP] . Wcat[4096,KP]^T  with split-K 8.
// FUSED k_castW: Wcat gathered + f2bf-cast inline during B-staging.
__global__ __launch_bounds__(256) void k5_gemm(const unsigned short* __restrict__ xinB,
                                               const float* __restrict__ Wih,
                                               const float* __restrict__ Whh,
                                               float* __restrict__ gpart) {
    __shared__ short As[4096];
    __shared__ short Bs[8192];

    const int n0 = blockIdx.x * 128;
    const int sp = blockIdx.y;
    const int kbeg   = (sp == 0) ? 0 : (5 + (sp - 1) * 4) * 64;
    const int ksteps = (sp == 0) ? 5 : 4;
    const int tid  = threadIdx.x;
    const int wave = tid >> 6;
    const int lane = tid & 63;
    const int wr = wave >> 1;
    const int wc = wave & 1;
    const int q4 = lane >> 4;
    const int ml = lane & 15;

    f32x4 acc[2][4];
#pragma unroll
    for (int i = 0; i < 2; ++i)
#pragma unroll
        for (int j = 0; j < 4; ++j) acc[i][j] = (f32x4){0.f, 0.f, 0.f, 0.f};

    for (int kk = 0; kk < ksteps; ++kk) {
        int k0 = kbeg + kk * 64;
        __syncthreads();
#pragma unroll
        for (int t = 0; t < 2; ++t) {
            int q = wave * 2 + t;
            ASYNC_CP16(xinB + (size_t)lane * KP + k0 + q * 8, &As[(q * 64) * 8]);
        }
        // B staging: inline cast from Wih/Whh (replaces WcatB ASYNC_CP16)
#pragma unroll
        for (int t = 0; t < 4; ++t) {
            int cb = t * 4 + wave;
            int q  = cb >> 1;
            int mb = (cb & 1) << 6;
            int g  = n0 + mb + lane;          // gate row (per-lane)
            int kq = k0 + q * 8;              // wave-uniform col base
            const float* rih = Wih + (size_t)g * 1035;
            const float* rhh = Whh + (size_t)g * 1024 - 1035;   // index by k directly
            union { unsigned short us[8]; bf16x8 v; } pk;
#pragma unroll
            for (int e2 = 0; e2 < 8; ++e2) {
                int k = kq + e2;              // wave-uniform -> scalar branch
                float vv;
                if (k < 1035)      vv = rih[k];
                else if (k < 2059) vv = rhh[k];
                else               vv = 0.f;
                pk.us[e2] = f2bf(vv);
            }
            *(bf16x8*)&Bs[(q * 128 + mb + lane) * 8] = pk.v;
        }
        __syncthreads();
#pragma unroll
        for (int s = 0; s < 2; ++s) {
            bf16x8 af[2], bfr[4];
#pragma unroll
            for (int i = 0; i < 2; ++i)
                af[i] = *(const bf16x8*)&As[((((s << 2) + q4) * 64) + wr * 32 + (i << 4) + ml) * 8];
#pragma unroll
            for (int j = 0; j < 4; ++j)
                bfr[j] = *(const bf16x8*)&Bs[((((s << 2) + q4) * 128) + wc * 64 + (j << 4) + ml) * 8];
#pragma unroll
            for (int i = 0; i < 2; ++i)
#pragma unroll
                for (int j = 0; j < 4; ++j)
                    acc[i][j] = __builtin_amdgcn_mfma_f32_16x16x32_bf16(af[i], bfr[j], acc[i][j], 0, 0, 0);
        }
    }
#pragma unroll
    for (int i = 0; i < 2; ++i)
#pragma unroll
        for (int j = 0; j < 4; ++j)
#pragma unroll
            for (int r = 0; r < 4; ++r) {
                int m = wr * 32 + (i << 4) + q4 * 4 + r;
                int n = n0 + wc * 64 + (j << 4) + ml;
                gpart[((size_t)sp * 64 + m) * 4096 + n] = acc[i][j][r];
            }
}

// k56: gates = sum_sp gpart + biases -> LSTM cell -> h,c; then fused LayerNorm+fin.
__global__ __launch_bounds__(256) void k56_lstm_ln(const float* __restrict__ gpart,
                                                   const float* __restrict__ bih,
                                                   const float* __restrict__ bhh,
                                                   const float* __restrict__ c0,
                                                   const float* __restrict__ lng,
                                                   const float* __restrict__ lnb,
                                                   const float* __restrict__ Wfin,
                                                   const float* __restrict__ bfin,
                                                   float* __restrict__ out) {
    int b = blockIdx.x, tid = threadIdx.x;
    __shared__ float red[8];
    float hn[4];
#pragma unroll
    for (int r = 0; r < 4; ++r) {
        int u = tid + (r << 8);
        float g[4];
#pragma unroll
        for (int gt = 0; gt < 4; ++gt) {
            int rr = gt * 1024 + u;
            float a = bih[rr] + bhh[rr];
#pragma unroll
            for (int sp = 0; sp < 8; ++sp)
                a += gpart[((size_t)sp * 64 + b) * 4096 + rr];
            g[gt] = a;
        }
        float cp = c0[b * 1024 + u];
        float si = 1.f / (1.f + __expf(-g[0]));
        float sf = 1.f / (1.f + __expf(-g[1]));
        float so = 1.f / (1.f + __expf(-g[3]));
        float cn = sf * cp + si * tanhf(g[2]);
        hn[r] = so * tanhf(cn);
        out[OUT_H + b * 1024 + u] = hn[r];
        out[OUT_C + b * 1024 + u] = cn;
    }
    // LayerNorm + final dot
    float mu = block_sum256(hn[0] + hn[1] + hn[2] + hn[3], red, tid) * (1.f / 1024.f);
    float d0 = hn[0] - mu, d1 = hn[1] - mu, d2 = hn[2] - mu, d3 = hn[3] - mu;
    float var = block_sum256(d0 * d0 + d1 * d1 + d2 * d2 + d3 * d3, red, tid) * (1.f / 1024.f);
    float rstd = rsqrtf(var + 1e-5f);
    float acc = (d0 * rstd * lng[tid]       + lnb[tid])       * Wfin[tid]
              + (d1 * rstd * lng[tid + 256] + lnb[tid + 256]) * Wfin[tid + 256]
              + (d2 * rstd * lng[tid + 512] + lnb[tid + 512]) * Wfin[tid + 512]
              + (d3 * rstd * lng[tid + 768] + lnb[tid + 768]) * Wfin[tid + 768];
    acc = block_sum256(acc, red, tid);
    if (tid == 0) out[OUT_FIN + b] = acc + bfin[0];
}

// ---------------------------------------------------------------------------
extern "C" void kernel_launch(void* const* d_in, const int* in_sizes, int n_in,
                              void* d_out, int out_size, void* d_ws, size_t ws_size,
                              hipStream_t stream) {
    (void)in_sizes; (void)n_in; (void)out_size; (void)ws_size;
    const float* x    = (const float*)d_in[0];
    const float* h0   = (const float*)d_in[1];
    const float* c0   = (const float*)d_in[2];
    const float* enc  = (const float*)d_in[3];
    const float* Wenc = (const float*)d_in[4];
    const float* Wdec = (const float*)d_in[5];
    const float* wval = (const float*)d_in[6];
    const float* Wg   = (const float*)d_in[7];
    const float* ev   = (const float*)d_in[8];
    const float* Wih  = (const float*)d_in[9];
    const float* Whh  = (const float*)d_in[10];
    const float* bih  = (const float*)d_in[11];
    const float* bhh  = (const float*)d_in[12];
    const float* lng  = (const float*)d_in[13];
    const float* lnb  = (const float*)d_in[14];
    const float* Wfin = (const float*)d_in[15];
    const float* bfin = (const float*)d_in[16];

    float* out  = (float*)d_out;
    float* ws   = (float*)d_ws;
    unsigned short* encB  = (unsigned short*)(ws + WS_ENCB);
    unsigned short* wencB = (unsigned short*)(ws + WS_WENCB);
    unsigned short* wdecB = (unsigned short*)(ws + WS_WDECB);
    unsigned short* h0B   = (unsigned short*)(ws + WS_H0B);
    float* dpart = ws + WS_DPART;
    float* part  = ws + WS_PART;
    float* ctxp  = ws + WS_CTXP;                                // alias over wdecB (dead after k1)
    float* gpart = ws + WS_GPART;                               // alias encB (dead after k3ab)
    unsigned short* xinB  = (unsigned short*)(ws + WS_XINB);    // alias encB

    k_cast      <<<17440, 256, 0, stream>>>(enc, Wenc, Wdec, h0, encB, wencB, wdecB, h0B);
    k1_gemm     <<<dim3(8, 8), 256, 0, stream>>>(h0B, wdecB, dpart);
    k2_scores   <<<2048, 512, 0, stream>>>(encB, wencB, dpart, wval, part);
    k3ab_context<<<dim3(16, 64), 256, 0, stream>>>(encB, part, ctxp, out);
    // encB region dead past k3ab -> safe for LSTM buffers (k4 writes xinB there)
    k4_sim      <<<64, 256, 0, stream>>>(ctxp, ev, Wg, x, h0, out, xinB);
    k5_gemm     <<<dim3(32, 8), 256, 0, stream>>>(xinB, Wih, Whh, gpart);
    k56_lstm_ln <<<64, 256, 0, stream>>>(gpart, bih, bhh, c0, lng, lnb, Wfin, bfin, out);
}